// Round 8
// baseline (77.716 us; speedup 1.0000x reference)
//
#include <hip/hip_runtime.h>
#include <hip/hip_bf16.h>
#include <math.h>

#define BB 16
#define CC 64
#define HW 4096
#define MM 1024
#define CK 8
#define CV 32
#define LOG2E 1.4426950408889634f

typedef float f32x4 __attribute__((ext_vector_type(4)));
typedef short s16x8 __attribute__((ext_vector_type(8)));

union U4 { uint4 u; s16x8 s; };

__device__ inline unsigned short bfu(float a) {           // RNE (prep only)
    __hip_bfloat16 h = __float2bfloat16(a);
    union { __hip_bfloat16 h; unsigned short u; } c; c.h = h; return c.u;
}
__device__ inline unsigned int pk2bf(float a, float b) {  // RNE pack
    return (unsigned int)bfu(a) | ((unsigned int)bfu(b) << 16);
}
__device__ inline unsigned int pk2bf_t(float a, float b) { // trunc pack (attn)
    return (__float_as_uint(a) >> 16) | (__float_as_uint(b) & 0xffff0000u);
}

// Workspace layout (bytes):
//   fxB bf16 [b][q][8]        @ 0        (1,048,576)
//   gxA bf16 [b][k][8]        @ 1048576  (262,144)
//   hxC bf16 [b][ch][k]       @ 1310720  (1,048,576)
//   wvB bf16 tiled [4][64][8] @ 2359296  (4,096)
#define FXB_OFF 0
#define GXA_OFF 1048576
#define HXC_OFF 1310720
#define WVB_OFF 2359296

// ---------------------------------------------------------------------------
// Kernel A: conv f/g/h split by OUTPUT channels: blockIdx.y = chunk
// (0=f, 1=g, 2..5=h quarters, 8 out-ch each). No input-channel split -> no
// channel-combine shfls; each thread does 8 out x 64 in = 512 FMA for its
// pixel. Pool via shfl_xor(1,2). hxC (transposed) staged via LDS.
// Grid (256, 6) x 256 thr -> 6144 waves -> 6 waves/SIMD.
// Wave pixel tile: 2 rows x 32 cols; col = chalf*32 + (l>>2)*2 + (l&1),
// row = rpair*2 + ((l>>1)&1)  => pool partners are l^1 (col), l^2 (row).
// ---------------------------------------------------------------------------
__global__ __launch_bounds__(256, 6) void prep_kernel(
    const float* __restrict__ x,
    const float* __restrict__ wf, const float* __restrict__ bf,
    const float* __restrict__ wg, const float* __restrict__ bg,
    const float* __restrict__ wh, const float* __restrict__ bh,
    const float* __restrict__ wv,
    unsigned short* __restrict__ fxB, unsigned short* __restrict__ gxA,
    unsigned short* __restrict__ hxC, unsigned short* __restrict__ wvB)
{
    __shared__ __align__(16) float wsm[8 * CC];              // chunk weights, 2KB
    __shared__ __align__(16) unsigned short sHp[64][8];      // h staging, 1KB

    int tid   = threadIdx.x;
    int chunk = blockIdx.y;            // 0=f 1=g 2..5=h
    const float* wsrc = (chunk == 0) ? wf : (chunk == 1) ? wg : (wh + (size_t)(chunk - 2) * 8 * CC);
    const float* bsrc = (chunk == 0) ? bf : (chunk == 1) ? bg : (bh + (chunk - 2) * 8);

    for (int i = tid; i < 8 * CC; i += 256) wsm[i] = wsrc[i];

    if (blockIdx.x == 0 && chunk == 0) {
        // wv bf16 A-fragments: wvB[ot][lane][8] = wv[ot*16+(l&15)][(l>>4)*8+j]
        int t = tid >> 6, ll = tid & 63;
        const float* wr = wv + (size_t)(t * 16 + (ll & 15)) * CV + ((ll >> 4) * 8);
        uint4 wu;
        wu.x = pk2bf(wr[0], wr[1]); wu.y = pk2bf(wr[2], wr[3]);
        wu.z = pk2bf(wr[4], wr[5]); wu.w = pk2bf(wr[6], wr[7]);
        *(uint4*)(wvB + (size_t)tid * 8) = wu;
    }
    __syncthreads();

    int wave = tid >> 6, l = tid & 63;
    int wp = blockIdx.x * 4 + wave;    // wave-position 0..1023
    int b  = wp >> 6;                  // 64 positions per batch
    int t2 = wp & 63;
    int rpair = t2 >> 1, chalf = t2 & 1;
    int col = chalf * 32 + (l >> 2) * 2 + (l & 1);
    int row = rpair * 2 + ((l >> 1) & 1);
    int pix = row * 64 + col;

    float o8[8];
#pragma unroll
    for (int o = 0; o < 8; ++o) o8[o] = bsrc[o];

    const float* xp = x + (size_t)b * CC * HW + pix;
#pragma unroll 4
    for (int c4 = 0; c4 < CC; c4 += 4) {
        float v0 = xp[(c4 + 0) * HW];
        float v1 = xp[(c4 + 1) * HW];
        float v2 = xp[(c4 + 2) * HW];
        float v3 = xp[(c4 + 3) * HW];
#pragma unroll
        for (int o = 0; o < 8; ++o) {
            float4 w = *(const float4*)&wsm[o * CC + c4];
            o8[o] = fmaf(w.x, v0, fmaf(w.y, v1, fmaf(w.z, v2, fmaf(w.w, v3, o8[o]))));
        }
    }

    if (chunk == 0) {
        // f(x): *log2e, bf16, full-res
        uint4 fu;
        fu.x = pk2bf(o8[0] * LOG2E, o8[1] * LOG2E);
        fu.y = pk2bf(o8[2] * LOG2E, o8[3] * LOG2E);
        fu.z = pk2bf(o8[4] * LOG2E, o8[5] * LOG2E);
        fu.w = pk2bf(o8[6] * LOG2E, o8[7] * LOG2E);
        *(uint4*)(fxB + (size_t)(b * HW + pix) * CK) = fu;
    } else {
        // 2x2 maxpool
#pragma unroll
        for (int o = 0; o < 8; ++o) {
            o8[o] = fmaxf(o8[o], __shfl_xor(o8[o], 1, 64));
            o8[o] = fmaxf(o8[o], __shfl_xor(o8[o], 2, 64));
        }
        int ppl = l >> 2;                          // pooled index in wave, 0..15
        if (chunk == 1) {
            if ((l & 3) == 0) {
                uint4 gu;
                gu.x = pk2bf(o8[0], o8[1]); gu.y = pk2bf(o8[2], o8[3]);
                gu.z = pk2bf(o8[4], o8[5]); gu.w = pk2bf(o8[6], o8[7]);
                *(uint4*)(gxA + (size_t)(b * MM + t2 * 16 + ppl) * CK) = gu;
            }
        } else {
            if ((l & 3) == 0) {
                uint4 hu;
                hu.x = pk2bf(o8[0], o8[1]); hu.y = pk2bf(o8[2], o8[3]);
                hu.z = pk2bf(o8[4], o8[5]); hu.w = pk2bf(o8[6], o8[7]);
                *(uint4*)&sHp[wave * 16 + ppl][0] = hu;
            }
            __syncthreads();
            // coalesced transposed store: block covers 64 consecutive pooled px
            int ch = tid >> 5, j = tid & 31;       // 8 ch x 32 pair-slots
            unsigned int v = (unsigned int)sHp[2 * j][ch]
                           | ((unsigned int)sHp[2 * j + 1][ch] << 16);
            int ppb = (blockIdx.x * 4 & 63) * 16;  // block's pooled-px base
            int chg = (chunk - 2) * 8 + ch;
            *(unsigned int*)(hxC + (size_t)(b * CV + chg) * MM + ppb + 2 * j) = v;
        }
    }
}

// ---------------------------------------------------------------------------
// Kernel B: MFMA flash attention, Q=64/block, 512 threads (8 waves).
// Wave w: qt-pair qg=w>>2 (Q-tiles 2qg,2qg+1), key-quarter kq=w&3 (256 keys).
// Partials (shift-free softmax -> plain sums) combined once through LDS;
// epilogue split by (qt = w&3, ot-half = w>>2). Key->row permutation
// perm(rho)=((rho&12)<<1)|(rho&3) makes the exp'd S^T fragment directly the
// PV B-fragment with zero cross-lane ops. Trunc bf16 pack in the hot loop.
// 1024 blocks, LDS 36KB -> 4 blocks/CU, target 8 waves/SIMD.
// ---------------------------------------------------------------------------
__global__ __launch_bounds__(512, 8) void attn_kernel(
    const float* __restrict__ x,
    const unsigned short* __restrict__ fxB, const unsigned short* __restrict__ gxA,
    const unsigned short* __restrict__ hxC, const unsigned short* __restrict__ wvB,
    const float* __restrict__ bv, const float* __restrict__ gamma,
    float* __restrict__ out)
{
    __shared__ __align__(16) float sAcc[4][4][64][8];  // [qt][kq][lane][8] 32KB
    __shared__ float sSum[4][4][64];                   // 4KB

    int tid = threadIdx.x;
    int l   = tid & 63;
    int w   = tid >> 6;                        // 0..7
    int qg  = w >> 2;                          // qt pair
    int kq  = w & 3;                           // key quarter
    int b   = blockIdx.x >> 6;                 // 64 blocks per batch
    int qb  = (blockIdx.x & 63) * 64;
    int q16 = l & 15;
    int h   = l >> 4;
    int prm = ((q16 & 12) << 1) | (q16 & 3);
    bool lo16 = (l < 16);

    // Q fragments (B-operand) for the wave's two Q-tiles
    U4 qf[2];
#pragma unroll
    for (int j = 0; j < 2; ++j) {
        int qt = qg * 2 + j;
        uint4 v = *(const uint4*)(fxB + (size_t)(b * HW + qb + qt * 16 + q16) * CK);
        if (!lo16) { v.x = 0; v.y = 0; v.z = 0; v.w = 0; }
        qf[j].u = v;
    }

    f32x4 zz = {0.f, 0.f, 0.f, 0.f};
    f32x4 acc0[2] = {zz, zz}, acc1[2] = {zz, zz};
    float ssum[2] = {0.f, 0.f};

    const unsigned short* gxb = gxA + (size_t)b * MM * CK;
    const unsigned short* hxb = hxC + (size_t)b * CV * MM;

#pragma unroll 2
    for (int gi = 0; gi < 8; ++gi) {
        int g = kq * 8 + gi;
        U4 ga, gb2, v0, v1;
        ga.u  = *(const uint4*)(gxb + (size_t)(g * 32 + prm) * CK);
        gb2.u = *(const uint4*)(gxb + (size_t)(g * 32 + prm + 4) * CK);
        v0.u  = *(const uint4*)(hxb + (size_t)(prm)     * MM + g * 32 + h * 8);
        v1.u  = *(const uint4*)(hxb + (size_t)(prm + 4) * MM + g * 32 + h * 8);

#pragma unroll
        for (int j = 0; j < 2; ++j) {
            f32x4 s0 = __builtin_amdgcn_mfma_f32_16x16x32_bf16(ga.s,  qf[j].s, zz, 0, 0, 0);
            f32x4 s1 = __builtin_amdgcn_mfma_f32_16x16x32_bf16(gb2.s, qf[j].s, zz, 0, 0, 0);
            // shift-free softmax: scores bounded; fx pre-scaled by log2e
            float e0 = __builtin_exp2f(s0.x), e1 = __builtin_exp2f(s0.y);
            float e2 = __builtin_exp2f(s0.z), e3 = __builtin_exp2f(s0.w);
            float e4 = __builtin_exp2f(s1.x), e5 = __builtin_exp2f(s1.y);
            float e6 = __builtin_exp2f(s1.z), e7 = __builtin_exp2f(s1.w);
            ssum[j] += ((e0 + e1) + (e2 + e3)) + ((e4 + e5) + (e6 + e7));
            U4 bp;
            bp.u.x = pk2bf_t(e0, e1); bp.u.y = pk2bf_t(e2, e3);
            bp.u.z = pk2bf_t(e4, e5); bp.u.w = pk2bf_t(e6, e7);
            acc0[j] = __builtin_amdgcn_mfma_f32_16x16x32_bf16(v0.s, bp.s, acc0[j], 0, 0, 0);
            acc1[j] = __builtin_amdgcn_mfma_f32_16x16x32_bf16(v1.s, bp.s, acc1[j], 0, 0, 0);
        }
    }

    // publish partials
#pragma unroll
    for (int j = 0; j < 2; ++j) {
        int qt = qg * 2 + j;
        *(f32x4*)&sAcc[qt][kq][l][0] = acc0[j];
        *(f32x4*)&sAcc[qt][kq][l][4] = acc1[j];
        sSum[qt][kq][l] = ssum[j];
    }
    __syncthreads();

    // wave w combines qt_f = w&3 and writes ot-half oth = w>>2
    int qt_f = w & 3;
    int oth  = w >> 2;
    f32x4 ca0 = zz, ca1 = zz;
    float cs = 0.f;
#pragma unroll
    for (int k2 = 0; k2 < 4; ++k2) {
        ca0 += *(const f32x4*)&sAcc[qt_f][k2][l][0];
        ca1 += *(const f32x4*)&sAcc[qt_f][k2][l][4];
        cs  += sSum[qt_f][k2][l];
    }
    cs += __shfl_xor(cs, 16, 64);
    cs += __shfl_xor(cs, 32, 64);
    float inv = 1.0f / cs;

    U4 mb;
    mb.u.x = pk2bf_t(ca0.x * inv, ca0.y * inv);
    mb.u.y = pk2bf_t(ca0.z * inv, ca0.w * inv);
    mb.u.z = pk2bf_t(ca1.x * inv, ca1.y * inv);
    mb.u.w = pk2bf_t(ca1.z * inv, ca1.w * inv);

    float gm = gamma[0];
    int q = qb + qt_f * 16 + q16;
    const float* xq = x + (size_t)b * CC * HW + q;
    float*       oq = out + (size_t)b * CC * HW + q;
#pragma unroll
    for (int i = 0; i < 2; ++i) {
        int ot = oth * 2 + i;
        U4 wva;
        wva.u = *(const uint4*)(wvB + (size_t)(ot * 64 + l) * CK);
        f32x4 d = __builtin_amdgcn_mfma_f32_16x16x32_bf16(wva.s, mb.s, zz, 0, 0, 0);
#pragma unroll
        for (int r = 0; r < 4; ++r) {
            int o = ot * 16 + h * 4 + r;
            oq[(size_t)o * HW] = xq[(size_t)o * HW] + gm * (d[r] + bv[o]);
        }
    }
}

extern "C" void kernel_launch(void* const* d_in, const int* in_sizes, int n_in,
                              void* d_out, int out_size, void* d_ws, size_t ws_size,
                              hipStream_t stream) {
    const float* x     = (const float*)d_in[0];
    const float* wf    = (const float*)d_in[1];
    const float* bf    = (const float*)d_in[2];
    const float* wg    = (const float*)d_in[3];
    const float* bg    = (const float*)d_in[4];
    const float* wh    = (const float*)d_in[5];
    const float* bh    = (const float*)d_in[6];
    const float* wv    = (const float*)d_in[7];
    const float* bv    = (const float*)d_in[8];
    const float* gamma = (const float*)d_in[9];
    float* out = (float*)d_out;
    char* ws = (char*)d_ws;

    unsigned short* fxB = (unsigned short*)(ws + FXB_OFF);
    unsigned short* gxA = (unsigned short*)(ws + GXA_OFF);
    unsigned short* hxC = (unsigned short*)(ws + HXC_OFF);
    unsigned short* wvB = (unsigned short*)(ws + WVB_OFF);

    // Kernel A: output-channel-split conv; grid (256 px-blocks, 6 chunks)
    prep_kernel<<<dim3(256, 6), 256, 0, stream>>>(x, wf, bf, wg, bg, wh, bh, wv,
                                                  fxB, gxA, hxC, wvB);
    // Kernel B: 1024 blocks x 512 thr; Q=64/block, (qt-pair x key-quarter) waves
    attn_kernel<<<1024, 512, 0, stream>>>(x, fxB, gxA, hxC, wvB, bv, gamma, out);
}

// Round 9
// 47.849 us; speedup vs baseline: 1.6242x; 1.6242x over previous
//
#include <hip/hip_runtime.h>
#include <hip/hip_bf16.h>
#include <math.h>

#define BB 16
#define CC 64
#define HW 4096
#define MM 1024
#define CK 8
#define CV 32
#define LOG2E 1.4426950408889634f

typedef float f32x4 __attribute__((ext_vector_type(4)));
typedef short s16x8 __attribute__((ext_vector_type(8)));

union U4 { uint4 u; s16x8 s; };

__device__ inline unsigned short bfu(float a) {           // RNE (prep only)
    __hip_bfloat16 h = __float2bfloat16(a);
    union { __hip_bfloat16 h; unsigned short u; } c; c.h = h; return c.u;
}
__device__ inline unsigned int pk2bf(float a, float b) {  // RNE pack
    return (unsigned int)bfu(a) | ((unsigned int)bfu(b) << 16);
}
__device__ inline unsigned int pk2bf_t(float a, float b) { // trunc pack (attn)
    return (__float_as_uint(a) >> 16) | (__float_as_uint(b) & 0xffff0000u);
}

// Workspace layout (bytes):
//   fxB bf16 [b][q][8]        @ 0        (1,048,576)
//   gxA bf16 [b][k][8]        @ 1048576  (262,144)
//   hxC bf16 [b][ch][k]       @ 1310720  (1,048,576)
//   wvB bf16 tiled [4][64][8] @ 2359296  (4,096)
#define FXB_OFF 0
#define GXA_OFF 1048576
#define HXC_OFF 1310720
#define WVB_OFF 2359296

// ---------------------------------------------------------------------------
// Kernel A: conv f/g/h split by OUTPUT channels: blockIdx.y = chunk
// (0=f, 1=g, 2..5=h quarters, 8 out-ch each). No input-channel split -> no
// channel-combine shfls. Pool via shfl_xor(1,2). hxC (transposed) staged via
// LDS. Grid (256, 6) x 256 thr.
// ---------------------------------------------------------------------------
__global__ __launch_bounds__(256, 6) void prep_kernel(
    const float* __restrict__ x,
    const float* __restrict__ wf, const float* __restrict__ bf,
    const float* __restrict__ wg, const float* __restrict__ bg,
    const float* __restrict__ wh, const float* __restrict__ bh,
    const float* __restrict__ wv,
    unsigned short* __restrict__ fxB, unsigned short* __restrict__ gxA,
    unsigned short* __restrict__ hxC, unsigned short* __restrict__ wvB)
{
    __shared__ __align__(16) float wsm[8 * CC];              // chunk weights, 2KB
    __shared__ __align__(16) unsigned short sHp[64][8];      // h staging, 1KB

    int tid   = threadIdx.x;
    int chunk = blockIdx.y;            // 0=f 1=g 2..5=h
    const float* wsrc = (chunk == 0) ? wf : (chunk == 1) ? wg : (wh + (size_t)(chunk - 2) * 8 * CC);
    const float* bsrc = (chunk == 0) ? bf : (chunk == 1) ? bg : (bh + (chunk - 2) * 8);

    for (int i = tid; i < 8 * CC; i += 256) wsm[i] = wsrc[i];

    if (blockIdx.x == 0 && chunk == 0) {
        // wv bf16 A-fragments: wvB[ot][lane][8] = wv[ot*16+(l&15)][(l>>4)*8+j]
        int t = tid >> 6, ll = tid & 63;
        const float* wr = wv + (size_t)(t * 16 + (ll & 15)) * CV + ((ll >> 4) * 8);
        uint4 wu;
        wu.x = pk2bf(wr[0], wr[1]); wu.y = pk2bf(wr[2], wr[3]);
        wu.z = pk2bf(wr[4], wr[5]); wu.w = pk2bf(wr[6], wr[7]);
        *(uint4*)(wvB + (size_t)tid * 8) = wu;
    }
    __syncthreads();

    int wave = tid >> 6, l = tid & 63;
    int wp = blockIdx.x * 4 + wave;    // wave-position 0..1023
    int b  = wp >> 6;                  // 64 positions per batch
    int t2 = wp & 63;
    int rpair = t2 >> 1, chalf = t2 & 1;
    int col = chalf * 32 + (l >> 2) * 2 + (l & 1);
    int row = rpair * 2 + ((l >> 1) & 1);
    int pix = row * 64 + col;

    float o8[8];
#pragma unroll
    for (int o = 0; o < 8; ++o) o8[o] = bsrc[o];

    const float* xp = x + (size_t)b * CC * HW + pix;
#pragma unroll 4
    for (int c4 = 0; c4 < CC; c4 += 4) {
        float v0 = xp[(c4 + 0) * HW];
        float v1 = xp[(c4 + 1) * HW];
        float v2 = xp[(c4 + 2) * HW];
        float v3 = xp[(c4 + 3) * HW];
#pragma unroll
        for (int o = 0; o < 8; ++o) {
            float4 w = *(const float4*)&wsm[o * CC + c4];
            o8[o] = fmaf(w.x, v0, fmaf(w.y, v1, fmaf(w.z, v2, fmaf(w.w, v3, o8[o]))));
        }
    }

    if (chunk == 0) {
        // f(x): *log2e, bf16, full-res
        uint4 fu;
        fu.x = pk2bf(o8[0] * LOG2E, o8[1] * LOG2E);
        fu.y = pk2bf(o8[2] * LOG2E, o8[3] * LOG2E);
        fu.z = pk2bf(o8[4] * LOG2E, o8[5] * LOG2E);
        fu.w = pk2bf(o8[6] * LOG2E, o8[7] * LOG2E);
        *(uint4*)(fxB + (size_t)(b * HW + pix) * CK) = fu;
    } else {
        // 2x2 maxpool
#pragma unroll
        for (int o = 0; o < 8; ++o) {
            o8[o] = fmaxf(o8[o], __shfl_xor(o8[o], 1, 64));
            o8[o] = fmaxf(o8[o], __shfl_xor(o8[o], 2, 64));
        }
        int ppl = l >> 2;                          // pooled index in wave, 0..15
        if (chunk == 1) {
            if ((l & 3) == 0) {
                uint4 gu;
                gu.x = pk2bf(o8[0], o8[1]); gu.y = pk2bf(o8[2], o8[3]);
                gu.z = pk2bf(o8[4], o8[5]); gu.w = pk2bf(o8[6], o8[7]);
                *(uint4*)(gxA + (size_t)(b * MM + t2 * 16 + ppl) * CK) = gu;
            }
        } else {
            if ((l & 3) == 0) {
                uint4 hu;
                hu.x = pk2bf(o8[0], o8[1]); hu.y = pk2bf(o8[2], o8[3]);
                hu.z = pk2bf(o8[4], o8[5]); hu.w = pk2bf(o8[6], o8[7]);
                *(uint4*)&sHp[wave * 16 + ppl][0] = hu;
            }
            __syncthreads();
            // coalesced transposed store: block covers 64 consecutive pooled px
            int ch = tid >> 5, j = tid & 31;       // 8 ch x 32 pair-slots
            unsigned int v = (unsigned int)sHp[2 * j][ch]
                           | ((unsigned int)sHp[2 * j + 1][ch] << 16);
            int ppb = (blockIdx.x * 4 & 63) * 16;  // block's pooled-px base
            int chg = (chunk - 2) * 8 + ch;
            *(unsigned int*)(hxC + (size_t)(b * CV + chg) * MM + ppb + 2 * j) = v;
        }
    }
}

// ---------------------------------------------------------------------------
// Kernel B: MFMA flash attention, Q=64/block, 512 threads (8 waves).
// Wave w: qt-pair qg=w>>2, key-quarter kq=w&3 (256 keys). Partials combined
// once through LDS (element-major layout -> lane-stride-1, conflict-free);
// epilogue split by (qt = w&3, ot-half = w>>2).
// launch_bounds(512,4): 128-VGPR cap -- R8's (512,8)=64-cap caused scratch
// spill (137MB WRITE_SIZE). 36KB LDS -> 2 blocks/CU, 4 waves/SIMD.
// ---------------------------------------------------------------------------
__global__ __launch_bounds__(512, 4) void attn_kernel(
    const float* __restrict__ x,
    const unsigned short* __restrict__ fxB, const unsigned short* __restrict__ gxA,
    const unsigned short* __restrict__ hxC, const unsigned short* __restrict__ wvB,
    const float* __restrict__ bv, const float* __restrict__ gamma,
    float* __restrict__ out)
{
    __shared__ float sAcc[4][4][8][64];   // [qt][kq][elem][lane] 32KB
    __shared__ float sSum[4][4][64];      // 4KB

    int tid = threadIdx.x;
    int l   = tid & 63;
    int w   = tid >> 6;                        // 0..7
    int qg  = w >> 2;                          // qt pair
    int kq  = w & 3;                           // key quarter
    int b   = blockIdx.x >> 6;                 // 64 blocks per batch
    int qb  = (blockIdx.x & 63) * 64;
    int q16 = l & 15;
    int h   = l >> 4;
    int prm = ((q16 & 12) << 1) | (q16 & 3);
    bool lo16 = (l < 16);

    // Q fragments (B-operand) for the wave's two Q-tiles
    U4 qf[2];
#pragma unroll
    for (int j = 0; j < 2; ++j) {
        int qt = qg * 2 + j;
        uint4 v = *(const uint4*)(fxB + (size_t)(b * HW + qb + qt * 16 + q16) * CK);
        if (!lo16) { v.x = 0; v.y = 0; v.z = 0; v.w = 0; }
        qf[j].u = v;
    }

    f32x4 zz = {0.f, 0.f, 0.f, 0.f};
    f32x4 acc0[2] = {zz, zz}, acc1[2] = {zz, zz};
    float ssum[2] = {0.f, 0.f};

    const unsigned short* gxb = gxA + (size_t)b * MM * CK;
    const unsigned short* hxb = hxC + (size_t)b * CV * MM;

#pragma unroll 2
    for (int gi = 0; gi < 8; ++gi) {
        int g = kq * 8 + gi;
        U4 ga, gb2, v0, v1;
        ga.u  = *(const uint4*)(gxb + (size_t)(g * 32 + prm) * CK);
        gb2.u = *(const uint4*)(gxb + (size_t)(g * 32 + prm + 4) * CK);
        v0.u  = *(const uint4*)(hxb + (size_t)(prm)     * MM + g * 32 + h * 8);
        v1.u  = *(const uint4*)(hxb + (size_t)(prm + 4) * MM + g * 32 + h * 8);

#pragma unroll
        for (int j = 0; j < 2; ++j) {
            f32x4 s0 = __builtin_amdgcn_mfma_f32_16x16x32_bf16(ga.s,  qf[j].s, zz, 0, 0, 0);
            f32x4 s1 = __builtin_amdgcn_mfma_f32_16x16x32_bf16(gb2.s, qf[j].s, zz, 0, 0, 0);
            // shift-free softmax: scores bounded; fx pre-scaled by log2e
            float e0 = __builtin_exp2f(s0.x), e1 = __builtin_exp2f(s0.y);
            float e2 = __builtin_exp2f(s0.z), e3 = __builtin_exp2f(s0.w);
            float e4 = __builtin_exp2f(s1.x), e5 = __builtin_exp2f(s1.y);
            float e6 = __builtin_exp2f(s1.z), e7 = __builtin_exp2f(s1.w);
            ssum[j] += ((e0 + e1) + (e2 + e3)) + ((e4 + e5) + (e6 + e7));
            U4 bp;
            bp.u.x = pk2bf_t(e0, e1); bp.u.y = pk2bf_t(e2, e3);
            bp.u.z = pk2bf_t(e4, e5); bp.u.w = pk2bf_t(e6, e7);
            acc0[j] = __builtin_amdgcn_mfma_f32_16x16x32_bf16(v0.s, bp.s, acc0[j], 0, 0, 0);
            acc1[j] = __builtin_amdgcn_mfma_f32_16x16x32_bf16(v1.s, bp.s, acc1[j], 0, 0, 0);
        }
    }

    // publish partials (element-major: lane-stride-1, conflict-free)
#pragma unroll
    for (int j = 0; j < 2; ++j) {
        int qt = qg * 2 + j;
#pragma unroll
        for (int e = 0; e < 4; ++e) {
            sAcc[qt][kq][e][l]     = acc0[j][e];
            sAcc[qt][kq][4 + e][l] = acc1[j][e];
        }
        sSum[qt][kq][l] = ssum[j];
    }
    __syncthreads();

    // wave w combines qt_f = w&3 and writes ot-half oth = w>>2
    int qt_f = w & 3;
    int oth  = w >> 2;
    f32x4 ca0 = zz, ca1 = zz;
    float cs = 0.f;
#pragma unroll
    for (int k2 = 0; k2 < 4; ++k2) {
#pragma unroll
        for (int e = 0; e < 4; ++e) {
            ca0[e] += sAcc[qt_f][k2][e][l];
            ca1[e] += sAcc[qt_f][k2][4 + e][l];
        }
        cs += sSum[qt_f][k2][l];
    }
    cs += __shfl_xor(cs, 16, 64);
    cs += __shfl_xor(cs, 32, 64);
    float inv = 1.0f / cs;

    U4 mb;
    mb.u.x = pk2bf_t(ca0.x * inv, ca0.y * inv);
    mb.u.y = pk2bf_t(ca0.z * inv, ca0.w * inv);
    mb.u.z = pk2bf_t(ca1.x * inv, ca1.y * inv);
    mb.u.w = pk2bf_t(ca1.z * inv, ca1.w * inv);

    float gm = gamma[0];
    int q = qb + qt_f * 16 + q16;
    const float* xq = x + (size_t)b * CC * HW + q;
    float*       oq = out + (size_t)b * CC * HW + q;
#pragma unroll
    for (int i = 0; i < 2; ++i) {
        int ot = oth * 2 + i;
        U4 wva;
        wva.u = *(const uint4*)(wvB + (size_t)(ot * 64 + l) * CK);
        f32x4 d = __builtin_amdgcn_mfma_f32_16x16x32_bf16(wva.s, mb.s, zz, 0, 0, 0);
#pragma unroll
        for (int r = 0; r < 4; ++r) {
            int o = ot * 16 + h * 4 + r;
            oq[(size_t)o * HW] = xq[(size_t)o * HW] + gm * (d[r] + bv[o]);
        }
    }
}

extern "C" void kernel_launch(void* const* d_in, const int* in_sizes, int n_in,
                              void* d_out, int out_size, void* d_ws, size_t ws_size,
                              hipStream_t stream) {
    const float* x     = (const float*)d_in[0];
    const float* wf    = (const float*)d_in[1];
    const float* bf    = (const float*)d_in[2];
    const float* wg    = (const float*)d_in[3];
    const float* bg    = (const float*)d_in[4];
    const float* wh    = (const float*)d_in[5];
    const float* bh    = (const float*)d_in[6];
    const float* wv    = (const float*)d_in[7];
    const float* bv    = (const float*)d_in[8];
    const float* gamma = (const float*)d_in[9];
    float* out = (float*)d_out;
    char* ws = (char*)d_ws;

    unsigned short* fxB = (unsigned short*)(ws + FXB_OFF);
    unsigned short* gxA = (unsigned short*)(ws + GXA_OFF);
    unsigned short* hxC = (unsigned short*)(ws + HXC_OFF);
    unsigned short* wvB = (unsigned short*)(ws + WVB_OFF);

    // Kernel A: output-channel-split conv; grid (256 px-blocks, 6 chunks)
    prep_kernel<<<dim3(256, 6), 256, 0, stream>>>(x, wf, bf, wg, bg, wh, bh, wv,
                                                  fxB, gxA, hxC, wvB);
    // Kernel B: 1024 blocks x 512 thr; Q=64/block, (qt-pair x key-quarter) waves
    attn_kernel<<<1024, 512, 0, stream>>>(x, fxB, gxA, hxC, wvB, bv, gamma, out);
}